// Round 7
// baseline (298.129 us; speedup 1.0000x reference)
//
#include <hip/hip_runtime.h>

// Decay-based linear recurrent scan:  S_t = d*S_{t-1} + (1-d)*kv_t ; out_t = q_t*S_t
// fp32, (T,B,H,V,D) = (128,16,8,25,64).
//
// Round-9 design: SINGLE-PASS decoupled-lookback chunked scan with the round-6
// measured-best memory geometry.
//   Evidence: combined service rate tracks per-t block footprint:
//     1 KB runs -> 3.1 TB/s (v4/v7), 16 KB runs -> 4.5 TB/s (p2, round 6).
//   But two-pass total (p1 ~35us + p2 71us) == single-pass v4 (102us): p1's full
//   kv read to emit 6.5 MB of summaries is pure tax. This kernel fuses it:
//   block (slab s, chunk c), slab = 1024 f4 channels (16 KB), chunk = 16 steps:
//     A: read own kv chunk, fold local B_c  (THE kv read; no pre-pass)
//        publish B_c to ws, __threadfence, device-scope flag.
//     B: spin on flags of chunks c'<c (same slab); Horner-fold S_in with A=d^16
//        (identical association to round-6 p2 -> same absmax 2e-3, passed).
//     C: replay chunk: kv re-read (L2-hot: this block just read it) + q read,
//        out = q*S, NT store (measured-best config).
//   Deadlock-free by capacity: 400 blocks x 256 thr, 0 LDS, ~48 VGPR
//   -> all 400 co-resident (>= 2 blocks/CU x 256 CUs) regardless of order.
//   Flags zeroed per-launch by a 1.6 KB hipMemsetAsync (graph-capturable),
//   so harness ws-poison cannot fake a 'done' flag.

#define T_DIM 128
#define CH4   51200             // float4 channels = B*H*V*D/4
#define VD    1600              // V*D (scalars)
#define NC    8                 // time chunks
#define LCH   (T_DIM / NC)      // 16 steps per chunk
#define THR   256               // threads per block
#define CPT   4                 // channel-chains per thread
#define BCH   (THR * CPT)       // f4-channels per block = 1024 (16 KB span)
#define BPC   (CH4 / BCH)       // 50 slabs
#define NBLK  (NC * BPC)        // 400 blocks

typedef float f32x4 __attribute__((ext_vector_type(4)));

__global__ __launch_bounds__(THR) void sss_lookback(
    const f32x4* __restrict__ q,
    const f32x4* __restrict__ kv,
    const float* __restrict__ decay,
    f32x4* __restrict__ wsum,          // [NC][CH4] chunk contributions
    unsigned int* __restrict__ flags,  // [NC*BPC] publish flags (zeroed pre-launch)
    f32x4* __restrict__ out)
{
    const int bid = blockIdx.x;
    const int c   = bid / BPC;                      // chunk (block-uniform)
    const int s   = bid % BPC;                      // slab
    const int cb  = s * BCH + threadIdx.x;          // chain-0 f4-channel

    int ci[CPT];
    f32x4 d[CPT], omd[CPT];
    #pragma unroll
    for (int cc = 0; cc < CPT; ++cc) {
        ci[cc] = cb + cc * THR;
        const int e0 = ci[cc] * 4;
        d[cc]   = *(const f32x4*)(decay + ((e0 / VD) & 7) * 64 + (e0 & 63));
        omd[cc] = 1.0f - d[cc];
    }

    const size_t tb = (size_t)c * LCH;

    // ---- phase A: local fold of own kv chunk from S=0 ----
    f32x4 B[CPT];
    #pragma unroll
    for (int cc = 0; cc < CPT; ++cc) B[cc] = (f32x4)0.0f;

    #pragma unroll
    for (int j = 0; j < LCH; ++j) {
        f32x4 k[CPT];
        #pragma unroll
        for (int cc = 0; cc < CPT; ++cc)
            k[cc] = kv[(tb + j) * CH4 + ci[cc]];
        #pragma unroll
        for (int cc = 0; cc < CPT; ++cc) {
            B[cc][0] = fmaf(d[cc][0], B[cc][0], omd[cc][0] * k[cc][0]);
            B[cc][1] = fmaf(d[cc][1], B[cc][1], omd[cc][1] * k[cc][1]);
            B[cc][2] = fmaf(d[cc][2], B[cc][2], omd[cc][2] * k[cc][2]);
            B[cc][3] = fmaf(d[cc][3], B[cc][3], omd[cc][3] * k[cc][3]);
        }
    }

    // publish B_c (chunk 7 has no consumers)
    if (c < NC - 1) {
        #pragma unroll
        for (int cc = 0; cc < CPT; ++cc)
            wsum[(size_t)c * CH4 + ci[cc]] = B[cc];
        __syncthreads();                  // all block stores issued
        if (threadIdx.x == 0) {
            __threadfence();              // device-visible before flag
            __hip_atomic_store(&flags[bid], 1u,
                               __ATOMIC_RELEASE, __HIP_MEMORY_SCOPE_AGENT);
        }
    }

    // A = d^16 (overlap ALU with the upcoming spin)
    f32x4 A[CPT], S[CPT];
    #pragma unroll
    for (int cc = 0; cc < CPT; ++cc) {
        f32x4 a = d[cc] * d[cc];  a = a * a;  a = a * a;  a = a * a;
        A[cc] = a;
        S[cc] = (f32x4)0.0f;
    }

    // ---- phase B: wait for predecessors (same slab), fold S_in ----
    if (c > 0) {
        if (threadIdx.x == 0) {
            for (int cp = 0; cp < c; ++cp) {
                while (__hip_atomic_load(&flags[cp * BPC + s],
                                         __ATOMIC_ACQUIRE,
                                         __HIP_MEMORY_SCOPE_AGENT) == 0u)
                    __builtin_amdgcn_s_sleep(8);
            }
        }
        __syncthreads();                  // flag seen -> data visible to block
        for (int cp = 0; cp < c; ++cp) {  // Horner: S = A*S + B_cp
            #pragma unroll
            for (int cc = 0; cc < CPT; ++cc) {
                const f32x4 Bp = wsum[(size_t)cp * CH4 + ci[cc]];
                S[cc][0] = fmaf(A[cc][0], S[cc][0], Bp[0]);
                S[cc][1] = fmaf(A[cc][1], S[cc][1], Bp[1]);
                S[cc][2] = fmaf(A[cc][2], S[cc][2], Bp[2]);
                S[cc][3] = fmaf(A[cc][3], S[cc][3], Bp[3]);
            }
        }
    }

    // ---- phase C: replay chunk (kv L2-hot) ; out = q * S, NT store ----
    #pragma unroll
    for (int j = 0; j < LCH; ++j) {
        f32x4 k[CPT], qq[CPT];
        #pragma unroll
        for (int cc = 0; cc < CPT; ++cc)
            k[cc] = kv[(tb + j) * CH4 + ci[cc]];
        #pragma unroll
        for (int cc = 0; cc < CPT; ++cc)
            qq[cc] = q[(tb + j) * CH4 + ci[cc]];
        #pragma unroll
        for (int cc = 0; cc < CPT; ++cc) {
            S[cc][0] = fmaf(d[cc][0], S[cc][0], omd[cc][0] * k[cc][0]);
            S[cc][1] = fmaf(d[cc][1], S[cc][1], omd[cc][1] * k[cc][1]);
            S[cc][2] = fmaf(d[cc][2], S[cc][2], omd[cc][2] * k[cc][2]);
            S[cc][3] = fmaf(d[cc][3], S[cc][3], omd[cc][3] * k[cc][3]);
            f32x4 o = qq[cc] * S[cc];
            __builtin_nontemporal_store(o, out + (tb + j) * CH4 + ci[cc]);
        }
    }
}

// ---------------------- fallback: single-kernel chunked scan (round-4, passed)
#define NW 8
__global__ __launch_bounds__(NW * 64) void sss_scan_v7(
    const f32x4* __restrict__ q,
    const f32x4* __restrict__ kv,
    const float* __restrict__ decay,
    f32x4* __restrict__ out)
{
    __shared__ f32x4 Blds[NW][64];
    const int w    = threadIdx.x >> 6;
    const int lane = threadIdx.x & 63;
    const int ci   = blockIdx.x * 64 + lane;
    const int e0   = ci * 4;
    const f32x4 d   = *(const f32x4*)(decay + ((e0 / VD) & 7) * 64 + (e0 & 63));
    const f32x4 omd = 1.0f - d;
    const size_t tbase = (size_t)w * (T_DIM / NW);
    const f32x4* kp = kv  + tbase * CH4 + ci;
    const f32x4* qp = q   + tbase * CH4 + ci;
    f32x4*       op = out + tbase * CH4 + ci;
    f32x4 B = (f32x4)0.0f;
    #pragma unroll
    for (int j = 0; j < T_DIM / NW; ++j) {
        f32x4 k = kp[(size_t)j * CH4];
        B[0] = fmaf(d[0], B[0], omd[0] * k[0]);
        B[1] = fmaf(d[1], B[1], omd[1] * k[1]);
        B[2] = fmaf(d[2], B[2], omd[2] * k[2]);
        B[3] = fmaf(d[3], B[3], omd[3] * k[3]);
    }
    Blds[w][lane] = B;
    __syncthreads();
    f32x4 A = d * d; A = A * A; A = A * A; A = A * A;
    f32x4 S = (f32x4)0.0f;
    for (int wp = 0; wp < w; ++wp) {
        const f32x4 Bp = Blds[wp][lane];
        S[0] = fmaf(A[0], S[0], Bp[0]);
        S[1] = fmaf(A[1], S[1], Bp[1]);
        S[2] = fmaf(A[2], S[2], Bp[2]);
        S[3] = fmaf(A[3], S[3], Bp[3]);
    }
    #pragma unroll
    for (int j = 0; j < T_DIM / NW; ++j) {
        f32x4 k  = kp[(size_t)j * CH4];
        f32x4 qq = qp[(size_t)j * CH4];
        S[0] = fmaf(d[0], S[0], omd[0] * k[0]);
        S[1] = fmaf(d[1], S[1], omd[1] * k[1]);
        S[2] = fmaf(d[2], S[2], omd[2] * k[2]);
        S[3] = fmaf(d[3], S[3], omd[3] * k[3]);
        f32x4 o = qq * S;
        __builtin_nontemporal_store(o, op + (size_t)j * CH4);
    }
}

extern "C" void kernel_launch(void* const* d_in, const int* in_sizes, int n_in,
                              void* d_out, int out_size, void* d_ws, size_t ws_size,
                              hipStream_t stream) {
    const f32x4* q     = (const f32x4*)d_in[0];
    const f32x4* kv    = (const f32x4*)d_in[1];
    const float* decay = (const float*)d_in[2];
    f32x4* out = (f32x4*)d_out;

    const size_t sum_bytes  = (size_t)NC * CH4 * sizeof(f32x4);   // 6.55 MB
    const size_t flag_bytes = (size_t)NBLK * sizeof(unsigned int);
    if (d_ws != nullptr && ws_size >= sum_bytes + flag_bytes) {
        f32x4*        wsum  = (f32x4*)d_ws;
        unsigned int* flags = (unsigned int*)((char*)d_ws + sum_bytes);
        hipMemsetAsync(flags, 0, flag_bytes, stream);   // graph-capturable
        sss_lookback<<<NBLK, THR, 0, stream>>>(q, kv, decay, wsum, flags, out);
    } else {
        sss_scan_v7<<<CH4 / 64, NW * 64, 0, stream>>>(q, kv, decay, out);
    }
}

// Round 8
// 267.978 us; speedup vs baseline: 1.1125x; 1.1125x over previous
//
#include <hip/hip_runtime.h>

// Decay-based linear recurrent scan:  S_t = d*S_{t-1} + (1-d)*kv_t ; out_t = q_t*S_t
// fp32, (T,B,H,V,D) = (128,16,8,25,64).
//
// Round-10 design: round-6 two-pass chunked scan + XCD-contiguous slab swizzle.
//   Evidence trail: service rate tracks contiguity of the concurrent stream
//   (1 KB->3.1, 2 KB->3.3, 16 KB slabs->4.5 TB/s); TLP falsified (v7);
//   per-wave MLP collapsed by compiler (v4/v6); lookback fusion refuted (r7:
//   VGPR 140, spin chain, 2.0 TB/s, 137 us).
//   New lever: blocks are dispatched round-robin over 8 XCDs (bid % 8), so
//   adjacent 16 KB slabs live on DIFFERENT XCDs -> each XCD's DRAM stream is
//   16 KB runs strided by 128 KB. Bijective slab swizzle (T1, m204 chunked
//   form) gives each XCD a contiguous 6-7-slab group => ~100-112 KB contiguous
//   per XCD per t-visit. Geometry/numerics identical to round 6 (passed, 2e-3).
//   Micro: q is NT-loaded in p2 (zero reuse; preserve kv MALL residency).

#define T_DIM 128
#define CH4   51200             // float4 channels = B*H*V*D/4
#define VD    1600              // V*D (scalars)
#define NC    8                 // time chunks
#define LCH   (T_DIM / NC)      // 16 steps per chunk
#define THR   256               // threads per block
#define CPT   4                 // channel-chains per thread
#define BCH   (THR * CPT)       // f4-channels per block = 1024 (16 KB span)
#define BPC   (CH4 / BCH)       // 50 slabs per chunk
#define NXCD  8

typedef float f32x4 __attribute__((ext_vector_type(4)));

// Bijective map [0,50) -> [0,50): blocks with the same XCD residue (l % 8)
// get CONTIGUOUS slab indices. Class sizes: residue 0,1 -> 7 slabs; 2..7 -> 6.
__device__ __forceinline__ int slab_swz(int l) {
    const int y = l & 7;        // XCD residue class (fixed rotation per chunk
    const int k = l >> 3;       //  doesn't break class-contiguity)
    return (y < 2 ? y * 7 : 14 + (y - 2) * 6) + k;
}

// ---------------------------------------------------------------- pass 1 ----
__global__ __launch_bounds__(THR) void sss_p1(
    const f32x4* __restrict__ kv,
    const float* __restrict__ decay,
    f32x4* __restrict__ ws)
{
    const int bid = blockIdx.x;
    const int c   = bid / BPC;                        // chunk (block-uniform)
    const int s   = slab_swz(bid % BPC);              // XCD-contiguous slab
    const int cb  = s * BCH + threadIdx.x;            // chain-0 f4-channel

    int ci[CPT];
    f32x4 d[CPT], omd[CPT], S[CPT];
    #pragma unroll
    for (int cc = 0; cc < CPT; ++cc) {
        ci[cc] = cb + cc * THR;
        const int e0 = ci[cc] * 4;
        d[cc]   = *(const f32x4*)(decay + ((e0 / VD) & 7) * 64 + (e0 & 63));
        omd[cc] = 1.0f - d[cc];
        S[cc]   = (f32x4)0.0f;
    }

    const size_t tb = (size_t)c * LCH;
    #pragma unroll
    for (int j = 0; j < LCH; ++j) {
        f32x4 k[CPT];
        #pragma unroll
        for (int cc = 0; cc < CPT; ++cc)
            k[cc] = kv[(tb + j) * CH4 + ci[cc]];
        #pragma unroll
        for (int cc = 0; cc < CPT; ++cc) {
            S[cc][0] = fmaf(d[cc][0], S[cc][0], omd[cc][0] * k[cc][0]);
            S[cc][1] = fmaf(d[cc][1], S[cc][1], omd[cc][1] * k[cc][1]);
            S[cc][2] = fmaf(d[cc][2], S[cc][2], omd[cc][2] * k[cc][2]);
            S[cc][3] = fmaf(d[cc][3], S[cc][3], omd[cc][3] * k[cc][3]);
        }
    }
    #pragma unroll
    for (int cc = 0; cc < CPT; ++cc)
        ws[(size_t)c * CH4 + ci[cc]] = S[cc];
}

// ---------------------------------------------------------------- pass 2 ----
__global__ __launch_bounds__(THR) void sss_p2(
    const f32x4* __restrict__ q,
    const f32x4* __restrict__ kv,
    const float* __restrict__ decay,
    const f32x4* __restrict__ ws,
    f32x4* __restrict__ out)
{
    const int bid = blockIdx.x;
    const int c   = bid / BPC;
    const int s   = slab_swz(bid % BPC);
    const int cb  = s * BCH + threadIdx.x;

    int ci[CPT];
    f32x4 d[CPT], omd[CPT], A[CPT], S[CPT];
    #pragma unroll
    for (int cc = 0; cc < CPT; ++cc) {
        ci[cc] = cb + cc * THR;
        const int e0 = ci[cc] * 4;
        d[cc]   = *(const f32x4*)(decay + ((e0 / VD) & 7) * 64 + (e0 & 63));
        omd[cc] = 1.0f - d[cc];
        f32x4 a = d[cc] * d[cc];  a = a * a;  a = a * a;  a = a * a;  // d^16
        A[cc] = a;
        S[cc] = (f32x4)0.0f;
    }

    // chunk-prefix fold: S_in = sum_{c'<c} A^(c-1-c') B_c'  (block-uniform trips)
    for (int cp = 0; cp < c; ++cp) {
        #pragma unroll
        for (int cc = 0; cc < CPT; ++cc) {
            const f32x4 B = ws[(size_t)cp * CH4 + ci[cc]];
            S[cc][0] = fmaf(A[cc][0], S[cc][0], B[0]);
            S[cc][1] = fmaf(A[cc][1], S[cc][1], B[1]);
            S[cc][2] = fmaf(A[cc][2], S[cc][2], B[2]);
            S[cc][3] = fmaf(A[cc][3], S[cc][3], B[3]);
        }
    }

    const size_t tb = (size_t)c * LCH;
    #pragma unroll
    for (int j = 0; j < LCH; ++j) {
        f32x4 k[CPT], qq[CPT];
        #pragma unroll
        for (int cc = 0; cc < CPT; ++cc)
            k[cc] = kv[(tb + j) * CH4 + ci[cc]];
        #pragma unroll
        for (int cc = 0; cc < CPT; ++cc)
            qq[cc] = __builtin_nontemporal_load(q + (tb + j) * CH4 + ci[cc]);
        #pragma unroll
        for (int cc = 0; cc < CPT; ++cc) {
            S[cc][0] = fmaf(d[cc][0], S[cc][0], omd[cc][0] * k[cc][0]);
            S[cc][1] = fmaf(d[cc][1], S[cc][1], omd[cc][1] * k[cc][1]);
            S[cc][2] = fmaf(d[cc][2], S[cc][2], omd[cc][2] * k[cc][2]);
            S[cc][3] = fmaf(d[cc][3], S[cc][3], omd[cc][3] * k[cc][3]);
            f32x4 o = qq[cc] * S[cc];
            __builtin_nontemporal_store(o, out + (tb + j) * CH4 + ci[cc]);
        }
    }
}

// ---------------------- fallback: single-kernel chunked scan (round-4, passed)
#define NW 8
__global__ __launch_bounds__(NW * 64) void sss_scan_v7(
    const f32x4* __restrict__ q,
    const f32x4* __restrict__ kv,
    const float* __restrict__ decay,
    f32x4* __restrict__ out)
{
    __shared__ f32x4 Blds[NW][64];
    const int w    = threadIdx.x >> 6;
    const int lane = threadIdx.x & 63;
    const int ci   = blockIdx.x * 64 + lane;
    const int e0   = ci * 4;
    const f32x4 d   = *(const f32x4*)(decay + ((e0 / VD) & 7) * 64 + (e0 & 63));
    const f32x4 omd = 1.0f - d;
    const size_t tbase = (size_t)w * (T_DIM / NW);
    const f32x4* kp = kv  + tbase * CH4 + ci;
    const f32x4* qp = q   + tbase * CH4 + ci;
    f32x4*       op = out + tbase * CH4 + ci;
    f32x4 B = (f32x4)0.0f;
    #pragma unroll
    for (int j = 0; j < T_DIM / NW; ++j) {
        f32x4 k = kp[(size_t)j * CH4];
        B[0] = fmaf(d[0], B[0], omd[0] * k[0]);
        B[1] = fmaf(d[1], B[1], omd[1] * k[1]);
        B[2] = fmaf(d[2], B[2], omd[2] * k[2]);
        B[3] = fmaf(d[3], B[3], omd[3] * k[3]);
    }
    Blds[w][lane] = B;
    __syncthreads();
    f32x4 A = d * d; A = A * A; A = A * A; A = A * A;
    f32x4 S = (f32x4)0.0f;
    for (int wp = 0; wp < w; ++wp) {
        const f32x4 Bp = Blds[wp][lane];
        S[0] = fmaf(A[0], S[0], Bp[0]);
        S[1] = fmaf(A[1], S[1], Bp[1]);
        S[2] = fmaf(A[2], S[2], Bp[2]);
        S[3] = fmaf(A[3], S[3], Bp[3]);
    }
    #pragma unroll
    for (int j = 0; j < T_DIM / NW; ++j) {
        f32x4 k  = kp[(size_t)j * CH4];
        f32x4 qq = qp[(size_t)j * CH4];
        S[0] = fmaf(d[0], S[0], omd[0] * k[0]);
        S[1] = fmaf(d[1], S[1], omd[1] * k[1]);
        S[2] = fmaf(d[2], S[2], omd[2] * k[2]);
        S[3] = fmaf(d[3], S[3], omd[3] * k[3]);
        f32x4 o = qq * S;
        __builtin_nontemporal_store(o, op + (size_t)j * CH4);
    }
}

extern "C" void kernel_launch(void* const* d_in, const int* in_sizes, int n_in,
                              void* d_out, int out_size, void* d_ws, size_t ws_size,
                              hipStream_t stream) {
    const f32x4* q     = (const f32x4*)d_in[0];
    const f32x4* kv    = (const f32x4*)d_in[1];
    const float* decay = (const float*)d_in[2];
    f32x4* out = (f32x4*)d_out;

    const size_t ws_need = (size_t)NC * CH4 * sizeof(f32x4);   // 6.55 MB
    if (d_ws != nullptr && ws_size >= ws_need) {
        f32x4* ws = (f32x4*)d_ws;
        sss_p1<<<NC * BPC, THR, 0, stream>>>(kv, decay, ws);
        sss_p2<<<NC * BPC, THR, 0, stream>>>(q, kv, decay, ws, out);
    } else {
        sss_scan_v7<<<CH4 / 64, NW * 64, 0, stream>>>(q, kv, decay, out);
    }
}